// Round 9
// baseline (1034.065 us; speedup 1.0000x reference)
//
#include <hip/hip_runtime.h>
#include <hip/hip_bf16.h>

#define Vn 25000
#define En 100000
#define NODE_IN 74
#define EDGE_IN 12
#define OUTD 64
#define EHID 128
#define NUM_STEPS 6

#define HPAD 68  // h_t row pitch (floats)

typedef __attribute__((ext_vector_type(8))) _Float16 half8;
typedef __attribute__((ext_vector_type(16))) float floatx16;

// h[v,o] = relu(node[v,:] @ Wp + bp)   [V,74]@[74,64]  (all fp32)
__global__ void proj_kernel(const float* __restrict__ node,
                            const float* __restrict__ Wp,
                            const float* __restrict__ bp,
                            float* __restrict__ h) {
  __shared__ float nf[NODE_IN];
  int v = blockIdx.x;
  int o = threadIdx.x;  // 64
  for (int i = o; i < NODE_IN; i += 64) nf[i] = node[(size_t)v * NODE_IN + i];
  __syncthreads();
  float acc = bp[o];
  for (int i = 0; i < NODE_IN; ++i) acc = fmaf(nf[i], Wp[i * OUTD + o], acc);
  h[(size_t)v * OUTD + o] = fmaxf(acc, 0.0f);
}

// f[e,k] = relu(edge[e,:] @ We1 + be1)   [E,12]@[12,128] fp32, stored f16
__global__ void edge_kernel(const float* __restrict__ ef,
                            const float* __restrict__ We1,
                            const float* __restrict__ be1,
                            _Float16* __restrict__ f) {
  __shared__ float es[EDGE_IN];
  int e = blockIdx.x;
  int k = threadIdx.x;  // 128
  if (k < EDGE_IN) es[k] = ef[(size_t)e * EDGE_IN + k];
  __syncthreads();
  float acc = be1[k];
  for (int j = 0; j < EDGE_IN; ++j) acc = fmaf(es[j], We1[j * EHID + k], acc);
  f[(size_t)e * EHID + k] = (_Float16)fmaxf(acc, 0.0f);
}

// B layout for 32x32x16_f16, wave-coalesced:
//   g = (((i*2 + c)*8 + s)*64 + lane)*8 + j
// holds f16(We2[k = s*16 + 8*(lane>>5) + j][col = i*64 + c*32 + (lane&31)]).
// Each (i,c,s) fragment load is one contiguous 1 KB wave transaction.
__global__ void w2r_kernel(const float* __restrict__ We2,
                           _Float16* __restrict__ w2s) {
  int g = blockIdx.x * 256 + threadIdx.x;  // < 524288
  int j = g & 7;
  int lane = (g >> 3) & 63;
  int s = (g >> 9) & 7;
  int c = (g >> 12) & 1;
  int i = g >> 13;
  int k = s * 16 + 8 * (lane >> 5) + j;
  int col = i * 64 + c * 32 + (lane & 31);
  w2s[g] = (_Float16)We2[(size_t)k * (OUTD * OUTD) + col];
}

// Fused per-step message kernel (32x32x16 f16 MFMA quadrants, 4 independent
// accumulator chains per wave for MFMA-pipe ILP):
// wave quadrant (eh = edge-half, ch = col-half) computes
//   msg[e in half, o in half] = sum_{i,k} (h[src,i]*F[e,k]) * We2[k, i*64+o]
__global__ __launch_bounds__(256) void msg_kernel(
    const float* __restrict__ h,
    const _Float16* __restrict__ f,
    const _Float16* __restrict__ w2s,
    const int* __restrict__ src,
    const int* __restrict__ dst,
    const float* __restrict__ be2,
    float* __restrict__ agg) {
  __shared__ float h_t[64 * HPAD];   // [i][e_local]
  __shared__ int s_dst[64];

  const int tid = threadIdx.x;
  const int wvq = tid >> 6;       // wave 0..3
  const int eh = wvq >> 1;        // edge half (32 edges)
  const int ch = wvq & 1;         // col half (32 outputs)
  const int lane = tid & 63;
  const int l31 = lane & 31;
  const int lh = lane >> 5;       // k-half selector within fragments
  const int e0 = blockIdx.x * 64;

  if (tid < 64) {
    int e = e0 + tid;
    s_dst[tid] = (e < En) ? dst[e] : -1;
  }
  {
    int e = tid & 63;
    int ib = tid >> 6;  // i-block 0..3 (16 i's each)
    int eg = e0 + e;
    int sv = (eg < En) ? src[eg] : 0;
    const float4* hp = reinterpret_cast<const float4*>(h + (size_t)sv * OUTD + ib * 16);
    for (int cc = 0; cc < 4; ++cc) {
      float4 val = hp[cc];
      int i4 = ib * 16 + cc * 4;
      h_t[(i4 + 0) * HPAD + e] = val.x;
      h_t[(i4 + 1) * HPAD + e] = val.y;
      h_t[(i4 + 2) * HPAD + e] = val.z;
      h_t[(i4 + 3) * HPAD + e] = val.w;
    }
  }
  __syncthreads();

  // A-fragments (f16): lane's edge row e = e0 + eh*32 + l31, 8 k-steps of 16.
  // A[m=l31][k = s*16 + 8*lh + j]
  half8 afr[8];
  {
    int e = e0 + eh * 32 + l31;
    if (e >= En) e = En - 1;  // clamped rows suppressed at scatter
    const _Float16* fr = f + (size_t)e * EHID + 8 * lh;
    for (int s = 0; s < 8; ++s)
      afr[s] = *reinterpret_cast<const half8*>(fr + s * 16);
  }

  // per-wave/lane base into the B layout
  const _Float16* w2b = w2s + ch * 4096 + lane * 8;

#define LOADB(dstv, ii)                                                     \
  {                                                                         \
    const _Float16* p_ = w2b + (size_t)(ii) * 8192;                         \
    dstv[0] = *reinterpret_cast<const half8*>(p_);                          \
    dstv[1] = *reinterpret_cast<const half8*>(p_ + 512);                    \
    dstv[2] = *reinterpret_cast<const half8*>(p_ + 1024);                   \
    dstv[3] = *reinterpret_cast<const half8*>(p_ + 1536);                   \
    dstv[4] = *reinterpret_cast<const half8*>(p_ + 2048);                   \
    dstv[5] = *reinterpret_cast<const half8*>(p_ + 2560);                   \
    dstv[6] = *reinterpret_cast<const half8*>(p_ + 3072);                   \
    dstv[7] = *reinterpret_cast<const half8*>(p_ + 3584);                   \
  }

  floatx16 acc0 = (floatx16){0.f};
  floatx16 acc1 = (floatx16){0.f};
  floatx16 acc2 = (floatx16){0.f};
  floatx16 acc3 = (floatx16){0.f};

  half8 ba[8], bb[8];
  LOADB(ba, 0);
  LOADB(bb, 1);

  // 4 independent C-chains (k-chunks of 32): chain c gets s = 2c, 2c+1.
#define BODY(iv, breg)                                                          \
  {                                                                             \
    _Float16 hh = (_Float16)h_t[(iv) * HPAD + eh * 32 + l31];                   \
    half8 hb = (half8){hh, hh, hh, hh, hh, hh, hh, hh};                         \
    half8 as0 = afr[0] * hb, as1 = afr[1] * hb, as2 = afr[2] * hb,              \
          as3 = afr[3] * hb, as4 = afr[4] * hb, as5 = afr[5] * hb,              \
          as6 = afr[6] * hb, as7 = afr[7] * hb;                                 \
    acc0 = __builtin_amdgcn_mfma_f32_32x32x16_f16(as0, breg[0], acc0, 0, 0, 0); \
    acc1 = __builtin_amdgcn_mfma_f32_32x32x16_f16(as2, breg[2], acc1, 0, 0, 0); \
    acc2 = __builtin_amdgcn_mfma_f32_32x32x16_f16(as4, breg[4], acc2, 0, 0, 0); \
    acc3 = __builtin_amdgcn_mfma_f32_32x32x16_f16(as6, breg[6], acc3, 0, 0, 0); \
    acc0 = __builtin_amdgcn_mfma_f32_32x32x16_f16(as1, breg[1], acc0, 0, 0, 0); \
    acc1 = __builtin_amdgcn_mfma_f32_32x32x16_f16(as3, breg[3], acc1, 0, 0, 0); \
    acc2 = __builtin_amdgcn_mfma_f32_32x32x16_f16(as5, breg[5], acc2, 0, 0, 0); \
    acc3 = __builtin_amdgcn_mfma_f32_32x32x16_f16(as7, breg[7], acc3, 0, 0, 0); \
  }

  for (int ii = 0; ii < 32; ++ii) {
    int i0 = 2 * ii;
    BODY(i0, ba);
    {
      int inx = (i0 + 2 < 64) ? i0 + 2 : 63;
      LOADB(ba, inx);
    }
    BODY(i0 + 1, bb);
    {
      int inx = (i0 + 3 < 64) ? i0 + 3 : 63;
      LOADB(bb, inx);
    }
  }

  // be2 contribution: msg[e,o] += sum_i h[src,i] * be2[i*64+o]  (exact 0 here)
  // K=64 over i in 4 MFMAs chained on acc0.
  {
    for (int s = 0; s < 4; ++s) {
      half8 ha, b2;
      for (int j = 0; j < 8; ++j) {
        int i = s * 16 + 8 * lh + j;
        ha[j] = (_Float16)h_t[i * HPAD + eh * 32 + l31];
        b2[j] = (_Float16)be2[i * 64 + ch * 32 + l31];
      }
      acc0 = __builtin_amdgcn_mfma_f32_32x32x16_f16(ha, b2, acc0, 0, 0, 0);
    }
  }

  floatx16 acc = (acc0 + acc1) + (acc2 + acc3);

  // scatter: C/D layout col=lane&31, row=(reg&3)+8*(reg>>2)+4*(lane>>5)
  int col = ch * 32 + l31;
  for (int reg = 0; reg < 16; ++reg) {
    int r = (reg & 3) + 8 * (reg >> 2) + 4 * lh;
    int d = s_dst[eh * 32 + r];
    if (d >= 0) atomicAdd(&agg[(size_t)d * OUTD + col], acc[reg]);
  }
}

// h_out = relu(agg + bias); re-zero agg; last step also writes fp32 d_out
__global__ void update_kernel(float* __restrict__ agg,
                              const float* __restrict__ bias,
                              float* __restrict__ hout,
                              float* __restrict__ dout, int last) {
  int g = blockIdx.x * 256 + threadIdx.x;
  if (g >= Vn * OUTD) return;
  float v = agg[g];
  agg[g] = 0.0f;
  float r = fmaxf(v + bias[g & 63], 0.0f);
  hout[g] = r;
  if (last) dout[g] = r;
}

extern "C" void kernel_launch(void* const* d_in, const int* in_sizes, int n_in,
                              void* d_out, int out_size, void* d_ws, size_t ws_size,
                              hipStream_t stream) {
  const float* node = (const float*)d_in[0];
  const float* edge = (const float*)d_in[1];
  const int* src = (const int*)d_in[2];
  const int* dst = (const int*)d_in[3];
  const float* Wp   = (const float*)d_in[4];
  const float* bp   = (const float*)d_in[5];
  const float* We1  = (const float*)d_in[6];
  const float* be1  = (const float*)d_in[7];
  const float* We2  = (const float*)d_in[8];
  const float* be2  = (const float*)d_in[9];
  const float* bias = (const float*)d_in[10];
  float* out = (float*)d_out;

  char* ws = (char*)d_ws;
  float* agg = (float*)(ws);                        // 6,400,000 B
  float* h_a = (float*)(ws + 6400000);              // 6,400,000 B
  float* h_b = (float*)(ws + 12800000);             // 6,400,000 B
  _Float16* f   = (_Float16*)(ws + 19200000);       // 25,600,000 B
  _Float16* w2s = (_Float16*)(ws + 44800000);       // 1,048,576 B

  hipMemsetAsync(agg, 0, (size_t)Vn * OUTD * sizeof(float), stream);
  proj_kernel<<<Vn, 64, 0, stream>>>(node, Wp, bp, h_a);
  edge_kernel<<<En, 128, 0, stream>>>(edge, We1, be1, f);
  w2r_kernel<<<(OUTD * OUTD * EHID) / 256, 256, 0, stream>>>(We2, w2s);

  float* hin = h_a;
  float* hout = h_b;
  for (int s = 0; s < NUM_STEPS; ++s) {
    msg_kernel<<<(En + 63) / 64, 256, 0, stream>>>(hin, f, w2s, src, dst, be2, agg);
    update_kernel<<<(Vn * OUTD + 255) / 256, 256, 0, stream>>>(
        agg, bias, hout, out, s == NUM_STEPS - 1);
    float* t = hin; hin = hout; hout = t;
  }
}

// Round 10
// 947.564 us; speedup vs baseline: 1.0913x; 1.0913x over previous
//
#include <hip/hip_runtime.h>
#include <hip/hip_bf16.h>

#define Vn 25000
#define En 100000
#define NODE_IN 74
#define EDGE_IN 12
#define OUTD 64
#define EHID 128
#define NUM_STEPS 6

#define EPB 128   // edges per block (8 waves: 4 edge-quarters x 2 col-halves)
#define HPAD 132  // h_t row pitch (f16 elements)

typedef __attribute__((ext_vector_type(8))) _Float16 half8;
typedef __attribute__((ext_vector_type(16))) float floatx16;

// h[v,o] = relu(node[v,:] @ Wp + bp)   [V,74]@[74,64]  (all fp32)
__global__ void proj_kernel(const float* __restrict__ node,
                            const float* __restrict__ Wp,
                            const float* __restrict__ bp,
                            float* __restrict__ h) {
  __shared__ float nf[NODE_IN];
  int v = blockIdx.x;
  int o = threadIdx.x;  // 64
  for (int i = o; i < NODE_IN; i += 64) nf[i] = node[(size_t)v * NODE_IN + i];
  __syncthreads();
  float acc = bp[o];
  for (int i = 0; i < NODE_IN; ++i) acc = fmaf(nf[i], Wp[i * OUTD + o], acc);
  h[(size_t)v * OUTD + o] = fmaxf(acc, 0.0f);
}

// f[e,k] = relu(edge[e,:] @ We1 + be1)   [E,12]@[12,128] fp32, stored f16
__global__ void edge_kernel(const float* __restrict__ ef,
                            const float* __restrict__ We1,
                            const float* __restrict__ be1,
                            _Float16* __restrict__ f) {
  __shared__ float es[EDGE_IN];
  int e = blockIdx.x;
  int k = threadIdx.x;  // 128
  if (k < EDGE_IN) es[k] = ef[(size_t)e * EDGE_IN + k];
  __syncthreads();
  float acc = be1[k];
  for (int j = 0; j < EDGE_IN; ++j) acc = fmaf(es[j], We1[j * EHID + k], acc);
  f[(size_t)e * EHID + k] = (_Float16)fmaxf(acc, 0.0f);
}

// B layout for 32x32x16_f16 (same as R8, proven correct):
//   g = (((i*2 + c)*8 + s)*64 + lane)*8 + j
// holds f16(We2[k = s*16 + 8*(lane>>5) + j][col = i*64 + c*32 + (lane&31)]).
// Per i the 16 KB tile is contiguous: ideal for block-level LDS staging.
__global__ void w2r_kernel(const float* __restrict__ We2,
                           _Float16* __restrict__ w2s) {
  int g = blockIdx.x * 256 + threadIdx.x;  // < 524288
  int j = g & 7;
  int lane = (g >> 3) & 63;
  int s = (g >> 9) & 7;
  int c = (g >> 12) & 1;
  int i = g >> 13;
  int k = s * 16 + 8 * (lane >> 5) + j;
  int col = i * 64 + c * 32 + (lane & 31);
  w2s[g] = (_Float16)We2[(size_t)k * (OUTD * OUTD) + col];
}

// Fused per-step message kernel: 128 edges/block, 8 waves.
// B tile (16 KB per i) staged once per block through LDS ping-pong;
// all 8 waves read fragments from LDS (lgkmcnt only in MFMA stream).
__global__ __launch_bounds__(512) void msg_kernel(
    const float* __restrict__ h,
    const _Float16* __restrict__ f,
    const _Float16* __restrict__ w2s,
    const int* __restrict__ src,
    const int* __restrict__ dst,
    const float* __restrict__ be2,
    float* __restrict__ agg) {
  __shared__ _Float16 h_t[64 * HPAD];       // [i][e_local], f16
  __shared__ half8 Bbuf[2][1024];           // ping-pong 16 KB B tiles
  __shared__ int s_dst[EPB];

  const int tid = threadIdx.x;
  const int wvq = tid >> 6;       // wave 0..7
  const int eh = wvq >> 1;        // edge quarter (32 edges)
  const int ch = wvq & 1;         // col half (32 outputs)
  const int lane = tid & 63;
  const int l31 = lane & 31;
  const int lh = lane >> 5;       // k-half selector within fragments
  const int e0 = blockIdx.x * EPB;

  if (tid < EPB) {
    int e = e0 + tid;
    s_dst[tid] = (e < En) ? dst[e] : -1;
  }
  {
    int e = tid & 127;
    int ib = tid >> 7;  // i-block 0..3 (16 i's each)
    int eg = e0 + e;
    int sv = (eg < En) ? src[eg] : 0;
    const float4* hp = reinterpret_cast<const float4*>(h + (size_t)sv * OUTD + ib * 16);
    for (int cc = 0; cc < 4; ++cc) {
      float4 val = hp[cc];
      int i4 = ib * 16 + cc * 4;
      h_t[(i4 + 0) * HPAD + e] = (_Float16)val.x;
      h_t[(i4 + 1) * HPAD + e] = (_Float16)val.y;
      h_t[(i4 + 2) * HPAD + e] = (_Float16)val.z;
      h_t[(i4 + 3) * HPAD + e] = (_Float16)val.w;
    }
  }

  // A-fragments (f16): lane's edge row e = e0 + eh*32 + l31, 8 k-steps of 16.
  half8 afr[8];
  {
    int e = e0 + eh * 32 + l31;
    if (e >= En) e = En - 1;  // clamped rows suppressed at scatter
    const _Float16* fr = f + (size_t)e * EHID + 8 * lh;
    for (int s = 0; s < 8; ++s)
      afr[s] = *reinterpret_cast<const half8*>(fr + s * 16);
  }

  // B tiles in half8 units: tile i = w2g[i*1024 .. i*1024+1024)
  const half8* w2g = reinterpret_cast<const half8*>(w2s);

  // prologue: stage tile 0
  {
    half8 s0 = w2g[tid];
    half8 s1 = w2g[512 + tid];
    Bbuf[0][tid] = s0;
    Bbuf[0][tid + 512] = s1;
  }
  __syncthreads();

  floatx16 acc0 = (floatx16){0.f};
  floatx16 acc1 = (floatx16){0.f};
  floatx16 acc2 = (floatx16){0.f};
  floatx16 acc3 = (floatx16){0.f};

  const int bfbase = ch * 512 + lane;  // half8 index of fragment s=0

  for (int i = 0; i < 64; ++i) {
    const int p = i & 1;
    // stage next tile: global -> regs (vmcnt drains at barrier)
    half8 s0, s1;
    if (i < 63) {
      const half8* gnx = w2g + (size_t)(i + 1) * 1024;
      s0 = gnx[tid];
      s1 = gnx[512 + tid];
    }

    // compute from LDS tile p
    const half8* Bp = Bbuf[p];
    half8 bfr[8];
    for (int s = 0; s < 8; ++s) bfr[s] = Bp[bfbase + s * 64];

    _Float16 hh = h_t[i * HPAD + eh * 32 + l31];
    half8 hb = (half8){hh, hh, hh, hh, hh, hh, hh, hh};
    half8 as0 = afr[0] * hb, as1 = afr[1] * hb, as2 = afr[2] * hb,
          as3 = afr[3] * hb, as4 = afr[4] * hb, as5 = afr[5] * hb,
          as6 = afr[6] * hb, as7 = afr[7] * hb;
    acc0 = __builtin_amdgcn_mfma_f32_32x32x16_f16(as0, bfr[0], acc0, 0, 0, 0);
    acc1 = __builtin_amdgcn_mfma_f32_32x32x16_f16(as2, bfr[2], acc1, 0, 0, 0);
    acc2 = __builtin_amdgcn_mfma_f32_32x32x16_f16(as4, bfr[4], acc2, 0, 0, 0);
    acc3 = __builtin_amdgcn_mfma_f32_32x32x16_f16(as6, bfr[6], acc3, 0, 0, 0);
    acc0 = __builtin_amdgcn_mfma_f32_32x32x16_f16(as1, bfr[1], acc0, 0, 0, 0);
    acc1 = __builtin_amdgcn_mfma_f32_32x32x16_f16(as3, bfr[3], acc1, 0, 0, 0);
    acc2 = __builtin_amdgcn_mfma_f32_32x32x16_f16(as5, bfr[5], acc2, 0, 0, 0);
    acc3 = __builtin_amdgcn_mfma_f32_32x32x16_f16(as7, bfr[7], acc3, 0, 0, 0);

    // write staged tile to the other buffer, then barrier
    if (i < 63) {
      Bbuf[1 - p][tid] = s0;
      Bbuf[1 - p][tid + 512] = s1;
    }
    __syncthreads();
  }

  // be2 contribution: msg[e,o] += sum_i h[src,i] * be2[i*64+o]  (exact 0 here)
  {
    for (int s = 0; s < 4; ++s) {
      half8 ha, b2;
      for (int j = 0; j < 8; ++j) {
        int i = s * 16 + 8 * lh + j;
        ha[j] = h_t[i * HPAD + eh * 32 + l31];
        b2[j] = (_Float16)be2[i * 64 + ch * 32 + l31];
      }
      acc0 = __builtin_amdgcn_mfma_f32_32x32x16_f16(ha, b2, acc0, 0, 0, 0);
    }
  }

  floatx16 acc = (acc0 + acc1) + (acc2 + acc3);

  // scatter: C/D layout col=lane&31, row=(reg&3)+8*(reg>>2)+4*(lane>>5)
  int col = ch * 32 + l31;
  for (int reg = 0; reg < 16; ++reg) {
    int r = (reg & 3) + 8 * (reg >> 2) + 4 * lh;
    int d = s_dst[eh * 32 + r];
    if (d >= 0) atomicAdd(&agg[(size_t)d * OUTD + col], acc[reg]);
  }
}

// h_out = relu(agg + bias); re-zero agg; last step also writes fp32 d_out
__global__ void update_kernel(float* __restrict__ agg,
                              const float* __restrict__ bias,
                              float* __restrict__ hout,
                              float* __restrict__ dout, int last) {
  int g = blockIdx.x * 256 + threadIdx.x;
  if (g >= Vn * OUTD) return;
  float v = agg[g];
  agg[g] = 0.0f;
  float r = fmaxf(v + bias[g & 63], 0.0f);
  hout[g] = r;
  if (last) dout[g] = r;
}

extern "C" void kernel_launch(void* const* d_in, const int* in_sizes, int n_in,
                              void* d_out, int out_size, void* d_ws, size_t ws_size,
                              hipStream_t stream) {
  const float* node = (const float*)d_in[0];
  const float* edge = (const float*)d_in[1];
  const int* src = (const int*)d_in[2];
  const int* dst = (const int*)d_in[3];
  const float* Wp   = (const float*)d_in[4];
  const float* bp   = (const float*)d_in[5];
  const float* We1  = (const float*)d_in[6];
  const float* be1  = (const float*)d_in[7];
  const float* We2  = (const float*)d_in[8];
  const float* be2  = (const float*)d_in[9];
  const float* bias = (const float*)d_in[10];
  float* out = (float*)d_out;

  char* ws = (char*)d_ws;
  float* agg = (float*)(ws);                        // 6,400,000 B
  float* h_a = (float*)(ws + 6400000);              // 6,400,000 B
  float* h_b = (float*)(ws + 12800000);             // 6,400,000 B
  _Float16* f   = (_Float16*)(ws + 19200000);       // 25,600,000 B
  _Float16* w2s = (_Float16*)(ws + 44800000);       // 1,048,576 B

  hipMemsetAsync(agg, 0, (size_t)Vn * OUTD * sizeof(float), stream);
  proj_kernel<<<Vn, 64, 0, stream>>>(node, Wp, bp, h_a);
  edge_kernel<<<En, 128, 0, stream>>>(edge, We1, be1, f);
  w2r_kernel<<<(OUTD * OUTD * EHID) / 256, 256, 0, stream>>>(We2, w2s);

  float* hin = h_a;
  float* hout = h_b;
  for (int s = 0; s < NUM_STEPS; ++s) {
    msg_kernel<<<(En + EPB - 1) / EPB, 512, 0, stream>>>(hin, f, w2s, src, dst, be2, agg);
    update_kernel<<<(Vn * OUTD + 255) / 256, 256, 0, stream>>>(
        agg, bias, hout, out, s == NUM_STEPS - 1);
    float* t = hin; hin = hout; hout = t;
  }
}